// Round 5
// baseline (659.105 us; speedup 1.0000x reference)
//
#include <hip/hip_runtime.h>
#include <stdint.h>

// Problem constants (must match reference)
#define B_DIM 16
#define S_DIM 512
#define N_HASH 8
#define M_BLOOM 4096
#define W_WIN 2
#define K_BLOCKS (2 * W_WIN + 1)                       // 5
#define OUT_ELEMS (B_DIM * K_BLOCKS * M_BLOOM * S_DIM) // 167,772,160 floats

// Per-block slab: 32 m-rows of one batch, all 5 shift-blocks.
// 16,640 B LDS -> 8 blocks/CU (LDS cap 160 KB), 32 waves/CU = 100% occupancy.
#define M_CHUNK 32
#define TILE_STRIDE 520                     // 4B guard + 512 data + 4B guard
#define TILE_BYTES (M_CHUNK * TILE_STRIDE)  // 16,640 B

typedef float fx4 __attribute__((ext_vector_type(4)));

// Write-once, no atomics. Block = (b, m-chunk of 32).
//   out[b, k*M + m, s] = #{n : hashes[b, s + k - W, n] % M == m}, 0 if OOB.
// LDS uint8 tile[m][s] with 4B zero guards so +/-2 shifted reads need no
// bounds checks.
__global__ __launch_bounds__(256) void bloom_window_kernel(
    const int* __restrict__ hashes, float* __restrict__ out) {
    __shared__ uint32_t tile32[TILE_BYTES / 4];
    uint8_t* tile = (uint8_t*)tile32;

    const int tid = threadIdx.x;
    const int b = blockIdx.x >> 7;          // 128 chunks per batch
    const int chunk = blockIdx.x & 127;
    const int m0 = chunk * M_CHUNK;

    // Phase 1: zero the tile (incl. guards).
    for (int i = tid; i < TILE_BYTES / 4; i += 256) tile32[i] = 0;
    __syncthreads();

    // Phase 2: histogram. Thread owns s-columns {2*tid, 2*tid+1} -> no LDS
    // write collisions (DS byte enables make different-byte same-word writes
    // from different lanes safe). Each block scans its batch's 16 KB of
    // hashes (L2-resident: 128 blocks share each batch's hashes).
    const int4* hp = (const int4*)hashes;
#pragma unroll
    for (int ss = 0; ss < 2; ++ss) {
        const int s = 2 * tid + ss;
        const int4 h01 = hp[(b * S_DIM + s) * 2 + 0];
        const int4 h23 = hp[(b * S_DIM + s) * 2 + 1];
        const int hv[8] = {h01.x, h01.y, h01.z, h01.w,
                           h23.x, h23.y, h23.z, h23.w};
#pragma unroll
        for (int n = 0; n < N_HASH; ++n) {
            const int m = hv[n] & (M_BLOOM - 1);
            const unsigned ml = (unsigned)(m - m0);
            if (ml < M_CHUNK) {
                tile[ml * TILE_STRIDE + 4 + s] += 1;
            }
        }
    }
    __syncthreads();

    // Phase 3: stream out 5 shifted copies, write-once, coalesced float4.
    // Thread owns one float4 column j; walks rows m (2 threads interleave).
    // k unrolled -> byte shift sh=(k-2)&3 is compile-time: k=2 is a single
    // aligned ds_read_b32; others are 2 reads + 1 alignbit.
    fx4* out4 = (fx4*)out;
    const int j = tid & 127;       // float4 index along s
    const int m_start = tid >> 7;  // 0 or 1

#pragma unroll
    for (int k = 0; k < K_BLOCKS; ++k) {
        const long long rowbase =
            ((long long)(b * K_BLOCKS + k) * M_BLOOM + m0) * (S_DIM / 4);
        const int sh = ((k - 2) & 3) * 8;  // 16,24,0,8,16 (compile-time)
#pragma unroll
        for (int m = m_start; m < M_CHUNK; m += 2) {
            const int base = m * TILE_STRIDE + 4 + 4 * j + (k - 2);
            const uint32_t* wp = (const uint32_t*)(tile + (base & ~3));
            uint32_t packed;
            if (sh == 0) {
                packed = wp[0];
            } else {
                const uint32_t lo = wp[0];
                const uint32_t hi = wp[1];
                packed = (lo >> sh) | (hi << (32 - sh));  // -> v_alignbit_b32
            }
            fx4 v;
            v.x = (float)(packed & 0xffu);          // v_cvt_f32_ubyte0
            v.y = (float)((packed >> 8) & 0xffu);   // v_cvt_f32_ubyte1
            v.z = (float)((packed >> 16) & 0xffu);  // v_cvt_f32_ubyte2
            v.w = (float)(packed >> 24);            // v_cvt_f32_ubyte3
            out4[rowbase + (long long)m * (S_DIM / 4) + j] = v;
        }
    }
}

extern "C" void kernel_launch(void* const* d_in, const int* in_sizes, int n_in,
                              void* d_out, int out_size, void* d_ws, size_t ws_size,
                              hipStream_t stream) {
    const int* hashes = (const int*)d_in[0];
    float* out = (float*)d_out;

    // 16 batches x 128 m-chunks = 2048 blocks; 16.6 KB LDS -> 8 blocks/CU.
    bloom_window_kernel<<<B_DIM * (M_BLOOM / M_CHUNK), 256, 0, stream>>>(hashes, out);
}